// Round 6
// baseline (103.451 us; speedup 1.0000x reference)
//
#include <hip/hip_runtime.h>
#include <hip/hip_bf16.h>

#ifndef __has_builtin
#define __has_builtin(x) 0
#endif

typedef __attribute__((ext_vector_type(8))) short short8;   // 8 bf16 = 4 VGPRs
typedef __attribute__((ext_vector_type(4))) float floatx4;  // MFMA C/D

__device__ __forceinline__ float fast_rcp(float x) {
#if __has_builtin(__builtin_amdgcn_rcpf)
    return __builtin_amdgcn_rcpf(x);
#else
    return 1.0f / x;
#endif
}

// Main-pipe exp2 replacing v_exp_f32 (measured ~51 cyc/wave64 across R3-R5 —
// trans-throughput-bound). Cubic on f=fract(t) with P(0)=1, P(1)=2 exactly
// (c1+c2+c3=1 -> continuous at integer boundaries); max rel err ~1.3e-4,
// well under the bf16 rounding (2^-9) the result immediately suffers.
// ~7 main-pipe insts = ~14 cyc/wave64 vs ~51 for the trans op.
__device__ __forceinline__ float poly_exp2(float t) {
    float fl = __builtin_floorf(t);          // v_floor_f32
    float f  = t - fl;                       // exact (Sterbenz)
    int   ri = (int)fl;                      // v_cvt_i32_f32
    float p  = fmaf(f, 0.07898f, 0.22519f);
    p = fmaf(f, p, 0.69583f);
    p = fmaf(f, p, 1.0f);
#if __has_builtin(__builtin_amdgcn_ldexpf)
    return __builtin_amdgcn_ldexpf(p, ri);   // v_ldexp_f32
#else
    return ldexpf(p, ri);
#endif
}

__device__ __forceinline__ unsigned pack_bf16(float a, float b) {
    __hip_bfloat162 h = __float22bfloat162_rn(make_float2(a, b));
    union { __hip_bfloat162 h2; unsigned u; } cv;
    cv.h2 = h;
    return cv.u;      // low half = a (k even), high = b (k odd)
}

#define VQ_K 256
#define BLK  256
#define T    8       // 16-row m-tiles per wave -> 128 m's/wave, 4096 waves

// Structure unchanged from R5 (correct, MFMA PV offload): lane (q=lane>>4,
// ml=lane&15) computes weights p = exp2(x.c2 + b) directly in 16x16x32 bf16
// A-fragment layout; O = P.[C|1] on the MFMA pipe; col 4 = denominator.
// Only change: poly_exp2 on the main pipe instead of v_exp_f32.
__global__ __launch_bounds__(BLK) void vq_mfma(const float* __restrict__ x,
                                               const float* __restrict__ center,
                                               float* __restrict__ out) {
    __shared__ float    s_c2[2056];        // staggered: off(k)=k*8+((k>>3)&3)*4
    __shared__ float    s_b[VQ_K];
    __shared__ unsigned s_v[8 * 64 * 4];   // prepacked V frags [chunk][lane][4]

    // ---- init: c2 / bias, one k per thread ----
    {
        const float L2E = 1.4426950408889634f;
        int k = threadIdx.x;
        float4 c = reinterpret_cast<const float4*>(center)[k];
        float b = -L2E * (c.x * c.x + c.y * c.y + c.z * c.z + c.w * c.w);
        int off = k * 8 + ((k >> 3) & 3) * 4;
        float s = 2.0f * L2E;
        s_c2[off + 0] = s * c.x;
        s_c2[off + 1] = s * c.y;
        s_c2[off + 2] = s * c.z;
        s_c2[off + 3] = s * c.w;
        s_b[k] = b;
    }
    // ---- init: V fragments. V[k][n] = c_k[n] (n<4), 1 (n==4), 0 else.
    for (int f = threadIdx.x; f < 512; f += BLK) {   // 8 chunks x 64 lanes
        int chunk = f >> 6, ln = f & 63;
        int n = ln & 15, q = ln >> 4;
#pragma unroll
        for (int r = 0; r < 4; ++r) {
            int k0 = chunk * 32 + q * 8 + 2 * r;
            float v0 = (n < 4) ? center[k0 * 4 + n]       : (n == 4 ? 1.f : 0.f);
            float v1 = (n < 4) ? center[(k0 + 1) * 4 + n] : (n == 4 ? 1.f : 0.f);
            s_v[f * 4 + r] = pack_bf16(v0, v1);
        }
    }
    __syncthreads();

    const int lane = threadIdx.x & 63;
    const int wv   = threadIdx.x >> 6;
    const int q    = lane >> 4;
    const int ml   = lane & 15;

    const int mbase = blockIdx.x * (4 * 16 * T) + wv * (16 * T);
    const float4* __restrict__ x4 = reinterpret_cast<const float4*>(x);

    float4 xr[T];
#pragma unroll
    for (int t = 0; t < T; ++t) xr[t] = x4[mbase + t * 16 + ml];

    floatx4 O[T];
#pragma unroll
    for (int t = 0; t < T; ++t) O[t] = (floatx4){0.f, 0.f, 0.f, 0.f};

    union AFrag { unsigned u[4]; short8 v; };

    for (int chunk = 0; chunk < 8; ++chunk) {
        AFrag areg[T];
#pragma unroll
        for (int jj = 0; jj < 4; ++jj) {
            int k0 = chunk * 32 + q * 8 + 2 * jj;
            int o0 = k0 * 8 + q * 4;               // stagger: (k0>>3)&3 == q
            float4 c2a = *reinterpret_cast<const float4*>(s_c2 + o0);
            float4 c2b = *reinterpret_cast<const float4*>(s_c2 + o0 + 8);
            float  ba  = s_b[k0];
            float  bb  = s_b[k0 + 1];
#pragma unroll
            for (int t = 0; t < T; ++t) {
                float s0 = fmaf(xr[t].x, c2a.x, ba);
                s0 = fmaf(xr[t].y, c2a.y, s0);
                s0 = fmaf(xr[t].z, c2a.z, s0);
                s0 = fmaf(xr[t].w, c2a.w, s0);
                float s1 = fmaf(xr[t].x, c2b.x, bb);
                s1 = fmaf(xr[t].y, c2b.y, s1);
                s1 = fmaf(xr[t].z, c2b.z, s1);
                s1 = fmaf(xr[t].w, c2b.w, s1);
                areg[t].u[jj] = pack_bf16(poly_exp2(s0), poly_exp2(s1));
            }
        }
        short8 bfrag = reinterpret_cast<const short8*>(s_v)[chunk * 64 + lane];
#pragma unroll
        for (int t = 0; t < T; ++t) {
            O[t] = __builtin_amdgcn_mfma_f32_16x16x32_bf16(areg[t].v, bfrag,
                                                           O[t], 0, 0, 0);
        }
    }

    // ---- epilogue: D col n = lane&15, row m = q*4 + reg; col 4 = den.
#pragma unroll
    for (int t = 0; t < T; ++t) {
#pragma unroll
        for (int r = 0; r < 4; ++r) {
            float den = __shfl(O[t][r], (lane & 48) + 4, 64);
            float val = O[t][r] * fast_rcp(den);
            int m = mbase + t * 16 + q * 4 + r;
            if (ml < 4) out[m * 4 + ml] = val;
        }
    }
}

extern "C" void kernel_launch(void* const* d_in, const int* in_sizes, int n_in,
                              void* d_out, int out_size, void* d_ws, size_t ws_size,
                              hipStream_t stream) {
    const float* x      = (const float*)d_in[0];   // [8, 262144] fp32
    const float* center = (const float*)d_in[1];   // [256, 4] fp32
    float* out = (float*)d_out;

    int nvec   = in_sizes[0] / 4;                  // 524288 m-vectors
    int blocks = nvec / (4 * 16 * T);              // 1024
    vq_mfma<<<blocks, BLK, 0, stream>>>(x, center, out);
}

// Round 7
// 93.487 us; speedup vs baseline: 1.1066x; 1.1066x over previous
//
#include <hip/hip_runtime.h>
#include <hip/hip_bf16.h>

#ifndef __has_builtin
#define __has_builtin(x) 0
#endif

typedef __attribute__((ext_vector_type(8))) short short8;   // 8 bf16 = 4 VGPRs
typedef __attribute__((ext_vector_type(4))) float floatx4;  // MFMA C/D

__device__ __forceinline__ float fast_exp2(float x) {
#if __has_builtin(__builtin_amdgcn_exp2f)
    return __builtin_amdgcn_exp2f(x);   // quarter-rate (~15 cyc/wave64) — cheaper
#else                                    // than any main-pipe poly once floor/cvt/
    return exp2f(x);                     // ldexp costs are counted (R6 regression)
#endif
}
__device__ __forceinline__ float fast_rcp(float x) {
#if __has_builtin(__builtin_amdgcn_rcpf)
    return __builtin_amdgcn_rcpf(x);
#else
    return 1.0f / x;
#endif
}
__device__ __forceinline__ unsigned pack_bf16(float a, float b) {
    __hip_bfloat162 h = __float22bfloat162_rn(make_float2(a, b));
    union { __hip_bfloat162 h2; unsigned u; } cv;
    cv.h2 = h;
    return cv.u;      // low half = a (k even), high = b (k odd)
}

#define VQ_K 256
#define BLK  256
#define T    4   // R7: halved from 8. 2048 blocks = 8/CU (LDS-exact), 8 waves/SIMD.
                 // R5's 44us @ T=8 was idle-bound (~2 waves/SIMD avg resident).

// Lane (q=lane>>4, ml=lane&15) computes weights p = exp2(x.c2 + b) directly in
// 16x16x32 bf16 A-fragment layout (m=ml, k=q*8+j); PV GEMM O = P.[C|1] on the
// MFMA pipe; D col 4 = denominator. bf16 P has fp32 exponent range -> no
// row-max pass needed. Issue floor/wave: ~1152 main x2cy + 256 exp x15cy.
__global__ __launch_bounds__(BLK, 8) void vq_mfma(const float* __restrict__ x,
                                                  const float* __restrict__ center,
                                                  float* __restrict__ out) {
    __shared__ float    s_c2[2056];        // staggered: off(k)=k*8+((k>>3)&3)*4
    __shared__ float    s_b[VQ_K];
    __shared__ unsigned s_v[8 * 64 * 4];   // prepacked V frags [chunk][lane][4]

    // ---- init: c2 / bias, one k per thread ----
    {
        const float L2E = 1.4426950408889634f;
        int k = threadIdx.x;
        float4 c = reinterpret_cast<const float4*>(center)[k];
        float b = -L2E * (c.x * c.x + c.y * c.y + c.z * c.z + c.w * c.w);
        int off = k * 8 + ((k >> 3) & 3) * 4;
        float s = 2.0f * L2E;
        s_c2[off + 0] = s * c.x;
        s_c2[off + 1] = s * c.y;
        s_c2[off + 2] = s * c.z;
        s_c2[off + 3] = s * c.w;
        s_b[k] = b;
    }
    // ---- init: V fragments. V[k][n] = c_k[n] (n<4), 1 (n==4), 0 else.
    for (int f = threadIdx.x; f < 512; f += BLK) {   // 8 chunks x 64 lanes
        int chunk = f >> 6, ln = f & 63;
        int n = ln & 15, q = ln >> 4;
#pragma unroll
        for (int r = 0; r < 4; ++r) {
            int k0 = chunk * 32 + q * 8 + 2 * r;
            float v0 = (n < 4) ? center[k0 * 4 + n]       : (n == 4 ? 1.f : 0.f);
            float v1 = (n < 4) ? center[(k0 + 1) * 4 + n] : (n == 4 ? 1.f : 0.f);
            s_v[f * 4 + r] = pack_bf16(v0, v1);
        }
    }
    __syncthreads();

    const int lane = threadIdx.x & 63;
    const int wv   = threadIdx.x >> 6;
    const int q    = lane >> 4;
    const int ml   = lane & 15;

    const int mbase = blockIdx.x * (4 * 16 * T) + wv * (16 * T);
    const float4* __restrict__ x4 = reinterpret_cast<const float4*>(x);

    float4 xr[T];
#pragma unroll
    for (int t = 0; t < T; ++t) xr[t] = x4[mbase + t * 16 + ml];

    floatx4 O[T];
#pragma unroll
    for (int t = 0; t < T; ++t) O[t] = (floatx4){0.f, 0.f, 0.f, 0.f};

    union AFrag { unsigned u[4]; short8 v; };

    for (int chunk = 0; chunk < 8; ++chunk) {
        AFrag areg[T];
#pragma unroll
        for (int jj = 0; jj < 4; ++jj) {
            int k0 = chunk * 32 + q * 8 + 2 * jj;
            int o0 = k0 * 8 + q * 4;               // stagger: (k0>>3)&3 == q
            float4 c2a = *reinterpret_cast<const float4*>(s_c2 + o0);
            float4 c2b = *reinterpret_cast<const float4*>(s_c2 + o0 + 8);
            float  ba  = s_b[k0];
            float  bb  = s_b[k0 + 1];
#pragma unroll
            for (int t = 0; t < T; ++t) {
                float s0 = fmaf(xr[t].x, c2a.x, ba);
                s0 = fmaf(xr[t].y, c2a.y, s0);
                s0 = fmaf(xr[t].z, c2a.z, s0);
                s0 = fmaf(xr[t].w, c2a.w, s0);
                float s1 = fmaf(xr[t].x, c2b.x, bb);
                s1 = fmaf(xr[t].y, c2b.y, s1);
                s1 = fmaf(xr[t].z, c2b.z, s1);
                s1 = fmaf(xr[t].w, c2b.w, s1);
                areg[t].u[jj] = pack_bf16(fast_exp2(s0), fast_exp2(s1));
            }
        }
        short8 bfrag = reinterpret_cast<const short8*>(s_v)[chunk * 64 + lane];
#pragma unroll
        for (int t = 0; t < T; ++t) {
            O[t] = __builtin_amdgcn_mfma_f32_16x16x32_bf16(areg[t].v, bfrag,
                                                           O[t], 0, 0, 0);
        }
    }

    // ---- epilogue: D col n = lane&15, row m = q*4 + reg; col 4 = den.
#pragma unroll
    for (int t = 0; t < T; ++t) {
#pragma unroll
        for (int r = 0; r < 4; ++r) {
            float den = __shfl(O[t][r], (lane & 48) + 4, 64);
            float val = O[t][r] * fast_rcp(den);
            int m = mbase + t * 16 + q * 4 + r;
            if (ml < 4) out[m * 4 + ml] = val;
        }
    }
}

extern "C" void kernel_launch(void* const* d_in, const int* in_sizes, int n_in,
                              void* d_out, int out_size, void* d_ws, size_t ws_size,
                              hipStream_t stream) {
    const float* x      = (const float*)d_in[0];   // [8, 262144] fp32
    const float* center = (const float*)d_in[1];   // [256, 4] fp32
    float* out = (float*)d_out;

    int nvec   = in_sizes[0] / 4;                  // 524288 m-vectors
    int blocks = nvec / (4 * 16 * T);              // 2048
    vq_mfma<<<blocks, BLK, 0, stream>>>(x, center, out);
}

// Round 8
// 84.735 us; speedup vs baseline: 1.2209x; 1.1033x over previous
//
#include <hip/hip_runtime.h>
#include <hip/hip_bf16.h>

#ifndef __has_builtin
#define __has_builtin(x) 0
#endif

typedef __attribute__((ext_vector_type(8))) short short8;   // 8 bf16 = 4 VGPRs
typedef __attribute__((ext_vector_type(4))) float floatx4;  // MFMA C/D

__device__ __forceinline__ float fast_exp2(float x) {
#if __has_builtin(__builtin_amdgcn_exp2f)
    return __builtin_amdgcn_exp2f(x);   // quarter-rate ~15cy/wave64; R6 showed poly is worse
#else
    return exp2f(x);
#endif
}
__device__ __forceinline__ float fast_rcp(float x) {
#if __has_builtin(__builtin_amdgcn_rcpf)
    return __builtin_amdgcn_rcpf(x);
#else
    return 1.0f / x;
#endif
}
__device__ __forceinline__ unsigned short bf16_of(float v) {
    union { __hip_bfloat16 b; unsigned short s; } cv;
    cv.b = __float2bfloat16(v);
    return cv.s;
}
__device__ __forceinline__ float bf16_back(unsigned short s) {
    union { __hip_bfloat16 b; unsigned short t; } cv;
    cv.t = s;
    return __bfloat162float(cv.b);
}
__device__ __forceinline__ unsigned bcat(unsigned short lo, unsigned short hi) {
    return (unsigned)lo | ((unsigned)hi << 16);   // slot j even = low half
}
__device__ __forceinline__ unsigned pack_bf16(float a, float b) {
    __hip_bfloat162 h = __float22bfloat162_rn(make_float2(a, b));
    union { __hip_bfloat162 h2; unsigned u; } cv;
    cv.h2 = h;
    return cv.u;
}

#define VQ_K 256
#define BLK  256
#define T    4      // 16-row m-tiles per wave; 2048 blocks

// R8: BOTH GEMMs on MFMA. S^T = C2ext * Xext via 16x16x32 bf16 with a
// 13-slot error-compensated split (d0-3: ch*xh, d4-7: ch*xl, d8-11: cl*xh,
// d12: bh*1, d13: bl*1) -> exponent accurate to ~3e-4 in fp32 accum.
// C/D layout gives lane (q,ml) the values S^T[k=32c+{4q+r | 16+4q+r}][m=ml];
// these feed the PV A-frag (slots k'=8q+j) IN-LANE; the slot->k permutation
// pi: k(q,j) = 32c + (j<4 ? 4q+j : 16+4q+j-4) is baked into the V prepack
// (V' rows permuted by pi), so runtime cost is zero. Loop is register-resident
// except 3 ds_read_b128 per 32-k chunk.
__global__ __launch_bounds__(BLK, 6) void vq_mfma(const float* __restrict__ x,
                                                  const float* __restrict__ center,
                                                  float* __restrict__ out) {
    __shared__ uint4 s_a[16 * 64];   // QK A-frags [kt][lane], 16 KB
    __shared__ uint4 s_v[8 * 64];    // PV V'-frags [chunk][lane], 8 KB

    const float L2E = 1.4426950408889634f;

    // ---- init: QK A-frag table (C2ext). Entry (kt, q, ml): row k = kt*16+ml.
    for (int f = threadIdx.x; f < 1024; f += BLK) {
        int kt = f >> 6, q = (f >> 4) & 3, ml = f & 15;
        int k = kt * 16 + ml;
        float4 c = reinterpret_cast<const float4*>(center)[k];
        float s = 2.0f * L2E;
        float c2f[4] = {s * c.x, s * c.y, s * c.z, s * c.w};
        unsigned short ch[4], cl[4];
#pragma unroll
        for (int d = 0; d < 4; ++d) {
            ch[d] = bf16_of(c2f[d]);
            cl[d] = bf16_of(c2f[d] - bf16_back(ch[d]));
        }
        float b = -L2E * (c.x * c.x + c.y * c.y + c.z * c.z + c.w * c.w);
        unsigned short bh = bf16_of(b);
        unsigned short bl = bf16_of(b - bf16_back(bh));
        uint4 e;
        if (q == 0) {
            e.x = bcat(ch[0], ch[1]); e.y = bcat(ch[2], ch[3]);
            e.z = e.x;                e.w = e.y;          // d4-7 pair with xl
        } else if (q == 1) {
            e.x = bcat(cl[0], cl[1]); e.y = bcat(cl[2], cl[3]);
            e.z = bcat(bh, bl);       e.w = 0;            // d12=bh*1, d13=bl*1
        } else {
            e.x = e.y = e.z = e.w = 0;
        }
        s_a[f] = e;
    }
    // ---- init: PV V'-frags with pi-permuted rows. Entry (c, q, n):
    // slot j -> actual k = 32c + (j<4 ? 4q+j : 16+4q+j-4); V[k][n] = c_k[n]
    // (n<4), 1 (n==4), 0 else.
    for (int f = threadIdx.x; f < 512; f += BLK) {
        int c = f >> 6, q = (f >> 4) & 3, n = f & 15;
        unsigned rr[4];
#pragma unroll
        for (int r = 0; r < 4; ++r) {
            int j0 = 2 * r, j1 = 2 * r + 1;
            int k0 = 32 * c + (j0 < 4 ? 4 * q + j0 : 16 + 4 * q + j0 - 4);
            int k1 = 32 * c + (j1 < 4 ? 4 * q + j1 : 16 + 4 * q + j1 - 4);
            float v0 = (n < 4) ? center[k0 * 4 + n] : (n == 4 ? 1.f : 0.f);
            float v1 = (n < 4) ? center[k1 * 4 + n] : (n == 4 ? 1.f : 0.f);
            rr[r] = bcat(bf16_of(v0), bf16_of(v1));
        }
        s_v[f] = make_uint4(rr[0], rr[1], rr[2], rr[3]);
    }
    __syncthreads();

    const int lane = threadIdx.x & 63;
    const int wv   = threadIdx.x >> 6;
    const int q    = lane >> 4;
    const int ml   = lane & 15;
    const int mbase = blockIdx.x * (4 * 16 * T) + wv * (16 * T);
    const float4* __restrict__ x4 = reinterpret_cast<const float4*>(x);

    union Frag { uint4 u4; unsigned u[4]; short8 v; };

    // ---- build Xext B-frags per m-tile: q0=[xh,xl], q1=[xh,1,1,0], q2/3=0
    Frag B[T];
#pragma unroll
    for (int t = 0; t < T; ++t) {
        float4 xv = x4[mbase + t * 16 + ml];
        unsigned short xh[4], xl[4];
        float xf[4] = {xv.x, xv.y, xv.z, xv.w};
#pragma unroll
        for (int d = 0; d < 4; ++d) {
            xh[d] = bf16_of(xf[d]);
            xl[d] = bf16_of(xf[d] - bf16_back(xh[d]));
        }
        unsigned h01 = bcat(xh[0], xh[1]), h23 = bcat(xh[2], xh[3]);
        unsigned l01 = bcat(xl[0], xl[1]), l23 = bcat(xl[2], xl[3]);
        const unsigned ONE2 = 0x3F803F80u;   // {1.0bf16, 1.0bf16}
        B[t].u[0] = (q <= 1) ? h01 : 0;
        B[t].u[1] = (q <= 1) ? h23 : 0;
        B[t].u[2] = (q == 0) ? l01 : ((q == 1) ? ONE2 : 0);
        B[t].u[3] = (q == 0) ? l23 : 0;
    }

    floatx4 O[T];
#pragma unroll
    for (int t = 0; t < T; ++t) O[t] = (floatx4){0.f, 0.f, 0.f, 0.f};

    const floatx4 Z4 = (floatx4){0.f, 0.f, 0.f, 0.f};

    for (int c = 0; c < 8; ++c) {        // 32 centers per chunk
        Frag a0, a1, vf;
        a0.u4 = s_a[(2 * c) * 64 + lane];
        a1.u4 = s_a[(2 * c + 1) * 64 + lane];
        vf.u4 = s_v[c * 64 + lane];
#pragma unroll
        for (int t = 0; t < T; ++t) {
            floatx4 S0 = __builtin_amdgcn_mfma_f32_16x16x32_bf16(a0.v, B[t].v, Z4, 0, 0, 0);
            floatx4 S1 = __builtin_amdgcn_mfma_f32_16x16x32_bf16(a1.v, B[t].v, Z4, 0, 0, 0);
            Frag p;
            p.u[0] = pack_bf16(fast_exp2(S0[0]), fast_exp2(S0[1]));
            p.u[1] = pack_bf16(fast_exp2(S0[2]), fast_exp2(S0[3]));
            p.u[2] = pack_bf16(fast_exp2(S1[0]), fast_exp2(S1[1]));
            p.u[3] = pack_bf16(fast_exp2(S1[2]), fast_exp2(S1[3]));
            O[t] = __builtin_amdgcn_mfma_f32_16x16x32_bf16(p.v, vf.v, O[t], 0, 0, 0);
        }
    }

    // ---- epilogue: D col n = lane&15, row m = q*4 + r; col 4 = denominator.
#pragma unroll
    for (int t = 0; t < T; ++t) {
#pragma unroll
        for (int r = 0; r < 4; ++r) {
            float den = __shfl(O[t][r], (lane & 48) + 4, 64);
            float val = O[t][r] * fast_rcp(den);
            int m = mbase + t * 16 + q * 4 + r;
            if (ml < 4) out[m * 4 + ml] = val;
        }
    }
}

extern "C" void kernel_launch(void* const* d_in, const int* in_sizes, int n_in,
                              void* d_out, int out_size, void* d_ws, size_t ws_size,
                              hipStream_t stream) {
    const float* x      = (const float*)d_in[0];   // [8, 262144] fp32
    const float* center = (const float*)d_in[1];   // [256, 4] fp32
    float* out = (float*)d_out;

    int nvec   = in_sizes[0] / 4;                  // 524288 m-vectors
    int blocks = nvec / (4 * 16 * T);              // 2048
    vq_mfma<<<blocks, BLK, 0, stream>>>(x, center, out);
}

// Round 9
// 83.365 us; speedup vs baseline: 1.2410x; 1.0164x over previous
//
#include <hip/hip_runtime.h>
#include <hip/hip_bf16.h>

#ifndef __has_builtin
#define __has_builtin(x) 0
#endif

typedef __attribute__((ext_vector_type(8))) short short8;   // 8 bf16 = 4 VGPRs
typedef __attribute__((ext_vector_type(4))) float floatx4;  // MFMA C/D

__device__ __forceinline__ float fast_exp2(float x) {
#if __has_builtin(__builtin_amdgcn_exp2f)
    return __builtin_amdgcn_exp2f(x);   // ~16 cyc/wave64; poly was worse (R6)
#else
    return exp2f(x);
#endif
}
__device__ __forceinline__ float fast_rcp(float x) {
#if __has_builtin(__builtin_amdgcn_rcpf)
    return __builtin_amdgcn_rcpf(x);
#else
    return 1.0f / x;
#endif
}
__device__ __forceinline__ unsigned short bf16_of(float v) {
    union { __hip_bfloat16 b; unsigned short s; } cv;
    cv.b = __float2bfloat16(v);
    return cv.s;
}
__device__ __forceinline__ float bf16_back(unsigned short s) {
    union { __hip_bfloat16 b; unsigned short t; } cv;
    cv.t = s;
    return __bfloat162float(cv.b);
}
__device__ __forceinline__ unsigned bcat(unsigned short lo, unsigned short hi) {
    return (unsigned)lo | ((unsigned)hi << 16);   // slot j even = low half
}
__device__ __forceinline__ unsigned pack_bf16(float a, float b) {
    __hip_bfloat162 h = __float22bfloat162_rn(make_float2(a, b));
    union { __hip_bfloat162 h2; unsigned u; } cv;
    cv.h2 = h;
    return cv.u;
}

#define VQ_K 256
#define BLK  256
#define T    2      // R9: halved again; with launch_bounds(256,8) -> 8 waves/SIMD

// R9 structure: same math as R8 (both GEMMs on MFMA; 13-slot error-compensated
// bf16 split for the exponent; pi-permutation baked into V'), but the fragment
// tables are built ONCE by vq_prep into d_ws (24 KB, L1/L2-resident) instead of
// per-block LDS init -> main kernel has no LDS table, no __syncthreads, no
// init ramp; table reads are coalesced global_load_dwordx4.

// ---- pre-kernel: 6 blocks x 256 threads, one table entry each ----
// ws layout (uint4): [0..1023] A-frags [kt*64+lane]; [1024..1535] V'-frags.
__global__ void vq_prep(const float* __restrict__ center, uint4* __restrict__ ws) {
    const float L2E = 1.4426950408889634f;
    int f = blockIdx.x * 256 + threadIdx.x;
    if (f < 1024) {
        // QK A-frag (C2ext). Entry (kt, q, ml): row k = kt*16+ml.
        int q = (f >> 4) & 3, ml = f & 15;
        int k = (f >> 6) * 16 + ml;
        float4 c = reinterpret_cast<const float4*>(center)[k];
        float s = 2.0f * L2E;
        float c2f[4] = {s * c.x, s * c.y, s * c.z, s * c.w};
        unsigned short ch[4], cl[4];
#pragma unroll
        for (int d = 0; d < 4; ++d) {
            ch[d] = bf16_of(c2f[d]);
            cl[d] = bf16_of(c2f[d] - bf16_back(ch[d]));
        }
        float b = -L2E * (c.x * c.x + c.y * c.y + c.z * c.z + c.w * c.w);
        unsigned short bh = bf16_of(b);
        unsigned short bl = bf16_of(b - bf16_back(bh));
        uint4 e;
        if (q == 0) {
            e.x = bcat(ch[0], ch[1]); e.y = bcat(ch[2], ch[3]);
            e.z = e.x;                e.w = e.y;           // d4-7 pair with xl
        } else if (q == 1) {
            e.x = bcat(cl[0], cl[1]); e.y = bcat(cl[2], cl[3]);
            e.z = bcat(bh, bl);       e.w = 0;             // d12=bh, d13=bl
        } else {
            e.x = e.y = e.z = e.w = 0;
        }
        ws[f] = e;
    } else {
        // PV V'-frag, rows permuted by pi: slot j -> k = 32c+(j<4?4q+j:16+4q+j-4)
        int g = f - 1024;                 // 0..511
        int c = g >> 6, q = (g >> 4) & 3, n = g & 15;
        unsigned rr[4];
#pragma unroll
        for (int r = 0; r < 4; ++r) {
            int j0 = 2 * r, j1 = 2 * r + 1;
            int k0 = 32 * c + (j0 < 4 ? 4 * q + j0 : 16 + 4 * q + j0 - 4);
            int k1 = 32 * c + (j1 < 4 ? 4 * q + j1 : 16 + 4 * q + j1 - 4);
            float v0 = (n < 4) ? center[k0 * 4 + n] : (n == 4 ? 1.f : 0.f);
            float v1 = (n < 4) ? center[k1 * 4 + n] : (n == 4 ? 1.f : 0.f);
            rr[r] = bcat(bf16_of(v0), bf16_of(v1));
        }
        ws[f] = make_uint4(rr[0], rr[1], rr[2], rr[3]);
    }
}

__global__ __launch_bounds__(BLK, 8) void vq_main(const float* __restrict__ x,
                                                  const uint4* __restrict__ ws,
                                                  float* __restrict__ out) {
    const int lane = threadIdx.x & 63;
    const int wv   = threadIdx.x >> 6;
    const int q    = lane >> 4;
    const int ml   = lane & 15;
    const int mbase = blockIdx.x * (4 * 16 * T) + wv * (16 * T);
    const float4* __restrict__ x4 = reinterpret_cast<const float4*>(x);
    const uint4* __restrict__ ta = ws;          // A-frags [kt*64+lane]
    const uint4* __restrict__ tv = ws + 1024;   // V'-frags [c*64+lane]

    union Frag { uint4 u4; unsigned u[4]; short8 v; };

    // ---- Xext B-frags: q0=[xh|xl], q1=[xh|1,1,0], q2/3=0 ----
    Frag B[T];
#pragma unroll
    for (int t = 0; t < T; ++t) {
        float4 xv = x4[mbase + t * 16 + ml];
        float xf[4] = {xv.x, xv.y, xv.z, xv.w};
        unsigned short xh[4], xl[4];
#pragma unroll
        for (int d = 0; d < 4; ++d) {
            xh[d] = bf16_of(xf[d]);
            xl[d] = bf16_of(xf[d] - bf16_back(xh[d]));
        }
        unsigned h01 = bcat(xh[0], xh[1]), h23 = bcat(xh[2], xh[3]);
        unsigned l01 = bcat(xl[0], xl[1]), l23 = bcat(xl[2], xl[3]);
        const unsigned ONE2 = 0x3F803F80u;      // {1.0bf16, 1.0bf16}
        B[t].u[0] = (q <= 1) ? h01 : 0;
        B[t].u[1] = (q <= 1) ? h23 : 0;
        B[t].u[2] = (q == 0) ? l01 : ((q == 1) ? ONE2 : 0);
        B[t].u[3] = (q == 0) ? l23 : 0;
    }

    floatx4 O[T];
#pragma unroll
    for (int t = 0; t < T; ++t) O[t] = (floatx4){0.f, 0.f, 0.f, 0.f};
    const floatx4 Z4 = (floatx4){0.f, 0.f, 0.f, 0.f};

    for (int c = 0; c < 8; ++c) {               // 32 centers per chunk
        Frag a0, a1, vf;
        a0.u4 = ta[(2 * c) * 64 + lane];        // coalesced 1KB/wave, L1-hot
        a1.u4 = ta[(2 * c + 1) * 64 + lane];
        vf.u4 = tv[c * 64 + lane];
#pragma unroll
        for (int t = 0; t < T; ++t) {
            floatx4 S0 = __builtin_amdgcn_mfma_f32_16x16x32_bf16(a0.v, B[t].v, Z4, 0, 0, 0);
            floatx4 S1 = __builtin_amdgcn_mfma_f32_16x16x32_bf16(a1.v, B[t].v, Z4, 0, 0, 0);
            Frag p;
            p.u[0] = pack_bf16(fast_exp2(S0[0]), fast_exp2(S0[1]));
            p.u[1] = pack_bf16(fast_exp2(S0[2]), fast_exp2(S0[3]));
            p.u[2] = pack_bf16(fast_exp2(S1[0]), fast_exp2(S1[1]));
            p.u[3] = pack_bf16(fast_exp2(S1[2]), fast_exp2(S1[3]));
            O[t] = __builtin_amdgcn_mfma_f32_16x16x32_bf16(p.v, vf.v, O[t], 0, 0, 0);
        }
    }

    // ---- epilogue: D col n = lane&15, row m = q*4 + r; col 4 = denominator.
#pragma unroll
    for (int t = 0; t < T; ++t) {
#pragma unroll
        for (int r = 0; r < 4; ++r) {
            float den = __shfl(O[t][r], (lane & 48) + 4, 64);
            float val = O[t][r] * fast_rcp(den);
            int m = mbase + t * 16 + q * 4 + r;
            if (ml < 4) out[m * 4 + ml] = val;
        }
    }
}

extern "C" void kernel_launch(void* const* d_in, const int* in_sizes, int n_in,
                              void* d_out, int out_size, void* d_ws, size_t ws_size,
                              hipStream_t stream) {
    const float* x      = (const float*)d_in[0];   // [8, 262144] fp32
    const float* center = (const float*)d_in[1];   // [256, 4] fp32
    float* out = (float*)d_out;
    uint4* ws  = (uint4*)d_ws;                     // 1536 uint4 = 24 KB

    vq_prep<<<6, 256, 0, stream>>>(center, ws);

    int nvec   = in_sizes[0] / 4;                  // 524288 m-vectors
    int blocks = nvec / (4 * 16 * T);              // 4096
    vq_main<<<blocks, BLK, 0, stream>>>(x, ws, out);
}